// Round 2
// baseline (928.085 us; speedup 1.0000x reference)
//
#include <hip/hip_runtime.h>
#include <cstdint>

#define K_CODES 8192
#define D_DIM   512
#define N_VEC   32768          // 16*2048
#define DECAY   0.99f
#define EPS_VQ  1e-5f
#define COMMIT  0.25f
#define MARGIN  0.25f          // stage-1 f16 dist error std ~0.03 -> ~8 sigma
                               // (key-packing clip adds <=0.016 abs, still ~7.5 sigma)

typedef _Float16 half_t;
typedef _Float16 half8 __attribute__((ext_vector_type(8)));
typedef _Float16 half4 __attribute__((ext_vector_type(4)));
typedef float    f32x4 __attribute__((ext_vector_type(4)));
typedef unsigned long long u64;

// async global->LDS DMA, 16B per lane; LDS dest must be linear in lane order
#define GL2L(g, l)                                                              \
    __builtin_amdgcn_global_load_lds(                                           \
        (const __attribute__((address_space(1))) unsigned int*)(g),             \
        (__attribute__((address_space(3))) unsigned int*)(l), 16, 0, 0)

__device__ __forceinline__ unsigned ordf(float f) {
    unsigned u = __float_as_uint(f);
    return (u & 0x80000000u) ? ~u : (u | 0x80000000u);
}
__device__ __forceinline__ float unordf(unsigned u) {
    u = (u & 0x80000000u) ? (u & 0x7FFFFFFFu) : ~u;
    return __uint_as_float(u);
}

// ---------------- output layout (float32, concatenated in return order) ---
// [0] loss | [1..16777217) z_q | [16777217..16809985) codes |
// [16809985..21004289) new_weight | [21004289..21012481) new_cs |
// [21012481..25206785) new_ema_w
//
// d_out scratch lifetimes:
//   A_hi f16 [out+4 ..)          32MB  (z_q region; z_q written last)
//   B_hi f16 [out+8388612 ..)     8MB  (z_q region)
//   partials [out+16809988 ..)   32MB  (new_weight/cs/ema_w region; dead
//                                       before those are memset/written)

// ---------------- K0: fp32 -> f16 cast ------------------------------------
__global__ __launch_bounds__(256)
void conv_half_kernel(const float* __restrict__ x, half_t* __restrict__ out) {
    int i = blockIdx.x * 256 + threadIdx.x;
    float4 v = ((const float4*)x)[i];
    half4 h = { (_Float16)v.x, (_Float16)v.y, (_Float16)v.z, (_Float16)v.w };
    *(half4*)(out + (size_t)i * 4) = h;
}

// ---------------- K1: wsq[k] = sum_d w[k][d]^2 (fp32) ---------------------
__global__ __launch_bounds__(256)
void wsq_kernel(const float* __restrict__ w, float* __restrict__ wsq) {
    int wave = threadIdx.x >> 6, lane = threadIdx.x & 63;
    int row  = blockIdx.x * 4 + wave;
    const float4* p = (const float4*)(w + (size_t)row * D_DIM);
    float4 a = p[lane], b = p[lane + 64];
    float s = a.x*a.x + a.y*a.y + a.z*a.z + a.w*a.w
            + b.x*b.x + b.y*b.y + b.z*b.z + b.w*b.w;
    #pragma unroll
    for (int off = 32; off; off >>= 1) s += __shfl_down(s, off);
    if (lane == 0) wsq[row] = s;
}

// ---------------- K2: single-pass f16 MFMA dist + top-2 -------------------
// v4: issue-slot diet.
//  * K-loop fully unrolled; 8 staging base pointers hoisted -> GL2L address
//    is base+const, folded into the 13-bit imm offset (no per-iter VALU).
//  * __launch_bounds__(256,4): VGPR cap 128 (was 84-by-choice) so hoisted
//    addresses stay in registers.
//  * Epilogue keys: a' = dot - wsq/2 + 1024 is strictly positive (dot is
//    >= -30 sigma away from -670), so float bits are order-preserving as
//    u32.  key = (bits & ~127) | col7 (clip err <=0.008 << MARGIN; any
//    distortion only shrinks the top-2 gap -> row flagged -> exact refine).
//    Per (row,lane) one uint2 {k1,k2}: per-wave overlay 8.7KB, LDS total
//    36864 -> 4 blocks/CU (was 3), and merges are cheap u32 min/max chains.
__global__ __launch_bounds__(256, 4)
void dist1_kernel(const half_t* __restrict__ A, const half_t* __restrict__ B,
                  const float* __restrict__ wsq, uint4* __restrict__ partial) {
    // staging view: As 128x64 f16 (16KB) | Bs 128x64 f16 (16KB)
    // epilogue view (after loop-final barrier, overlaid):
    //   per wave @ wave*8704: uint2 key[64][17]   (row-stride 17 kills the
    //     b64 write conflict beyond the 4-slot floor)
    //   fm @ 34816: uint2[2][128]
    __shared__ __align__(16) char smem[36864];
    half_t* As = (half_t*)smem;
    half_t* Bs = (half_t*)(smem + 16384);

    const int k0 = blockIdx.x * 128;      // codes
    const int n0 = blockIdx.y * 128;      // z rows
    const int t    = threadIdx.x;
    const int lane = t & 63;
    const int wave = t >> 6;
    const int wm = (wave >> 1) * 64;
    const int wn = (wave & 1) * 64;
    const int l15 = lane & 15;
    const int q   = lane >> 4;

    // hoisted staging addresses (constant across the K loop)
    const half_t* ga[4]; const half_t* gb[4]; half_t* lA[4]; half_t* lB[4];
    #pragma unroll
    for (int it = 0; it < 4; ++it) {
        int idx  = t + 256 * it;            // 16B chunk id, lane-linear
        int row  = idx >> 3;
        int col8 = (idx & 7) ^ (row & 7);   // XOR-swizzled global column
        ga[it] = A + (size_t)(n0 + row) * D_DIM + col8 * 8;
        gb[it] = B + (size_t)(k0 + row) * D_DIM + col8 * 8;
        lA[it] = As + idx * 8;
        lB[it] = Bs + idx * 8;
    }

    f32x4 acc[4][4];
    #pragma unroll
    for (int mi = 0; mi < 4; ++mi)
        #pragma unroll
        for (int ni = 0; ni < 4; ++ni) acc[mi][ni] = (f32x4)0.0f;

    #pragma unroll
    for (int c = 0; c < 8; ++c) {
        #pragma unroll
        for (int it = 0; it < 4; ++it) {
            GL2L(ga[it] + c * 64, lA[it]);   // +c*128B folds into imm offset
            GL2L(gb[it] + c * 64, lB[it]);
        }
        __syncthreads();
        #pragma unroll
        for (int kk = 0; kk < 2; ++kk) {
            half8 af[4], bf[4];
            const int cpos = ((kk * 4 + q) ^ (l15 & 7)) * 8;   // de-swizzle
            #pragma unroll
            for (int mi = 0; mi < 4; ++mi)
                af[mi] = *(const half8*)&As[(wm + mi * 16 + l15) * 64 + cpos];
            #pragma unroll
            for (int ni = 0; ni < 4; ++ni)
                bf[ni] = *(const half8*)&Bs[(wn + ni * 16 + l15) * 64 + cpos];
            #pragma unroll
            for (int mi = 0; mi < 4; ++mi)
                #pragma unroll
                for (int ni = 0; ni < 4; ++ni)
                    acc[mi][ni] = __builtin_amdgcn_mfma_f32_16x16x32_f16(
                        af[mi], bf[ni], acc[mi][ni], 0, 0, 0);
        }
        __syncthreads();
    }
    // loop ended with __syncthreads(): every wave is past its last tile
    // ds_read, so the overlay below is race-free.

    uint2* kp  = (uint2*)(smem + wave * 8704);
    uint2* fmp = (uint2*)(smem + 34816);

    float wb[4]; unsigned cb[4];
    #pragma unroll
    for (int ni = 0; ni < 4; ++ni) {
        wb[ni] = 1024.0f - 0.5f * wsq[k0 + wn + ni * 16 + l15];
        cb[ni] = (unsigned)(wn + ni * 16 + l15);
    }

    // phase 1: per-lane top-2 keys of its 4 cols, per row; stash transposed
    #pragma unroll
    for (int mi = 0; mi < 4; ++mi) {
        #pragma unroll
        for (int r = 0; r < 4; ++r) {
            unsigned k1 = 0u, k2 = 0u;
            #pragma unroll
            for (int ni = 0; ni < 4; ++ni) {
                float a = acc[mi][ni][r] + wb[ni];
                unsigned key = (__float_as_uint(a) & 0xFFFFFF80u) | cb[ni];
                unsigned lo = min(k1, key);
                k1 = max(k1, key);
                k2 = max(k2, lo);
            }
            int row = mi * 16 + q * 4 + r;          // 0..63 within wave tile
            kp[row * 17 + l15] = make_uint2(k1, k2);
        }
    }
    __syncthreads();

    // phase 2: lane owns in-wave row == lane; serial 16-way merge
    {
        const int rb = lane * 17;
        uint2 e0 = kp[rb];
        unsigned W1 = e0.x, W2 = e0.y;
        #pragma unroll
        for (int j = 1; j < 16; ++j) {
            uint2 e = kp[rb + j];
            unsigned lo = min(W1, e.x);
            W1 = max(W1, e.x);
            W2 = max(max(W2, lo), e.y);             // v_max3_u32
        }
        fmp[(wave & 1) * 128 + wm + lane] = make_uint2(W1, W2);
    }
    __syncthreads();

    // phase 3: merge the two 64-col halves, pack partial (same format)
    if (t < 128) {
        uint2 a = fmp[t], b = fmp[128 + t];
        unsigned W1 = max(a.x, b.x);
        unsigned W2 = max(max(min(a.x, b.x), a.y), b.y);
        unsigned col = (unsigned)k0 + (W1 & 127u);
        float v1 = __uint_as_float(W1 & 0xFFFFFF80u);
        float v2 = __uint_as_float(W2 & 0xFFFFFF80u);
        float d1 = 2048.0f - 2.0f * v1;             // dist = -2*(a'-1024)
        float d2 = 2048.0f - 2.0f * v2;
        partial[(size_t)blockIdx.x * N_VEC + n0 + t] =
            make_uint4(col, ordf(d1), ordf(d2), 0u);
    }
}

// ---------------- K3: merge 64 partials/row, flag ambiguous rows ----------
__global__ __launch_bounds__(256)
void reduce_top2_kernel(const uint4* __restrict__ partial,
                        int* __restrict__ codes_i, float* __restrict__ codes_f,
                        int* __restrict__ cnt, int* __restrict__ list) {
    int row = blockIdx.x * 256 + threadIdx.x;
    u64 k1 = ~0ull, k2 = ~0ull;
    unsigned vm2 = 0xFFFFFFFFu;
    for (int kb = 0; kb < 64; ++kb) {
        uint4 e = partial[(size_t)kb * N_VEC + row];
        u64 k = ((u64)e.y << 32) | e.x;
        if (k < k1) { k2 = k1; k1 = k; }
        else if (k < k2) k2 = k;
        vm2 = min(vm2, e.z);
    }
    unsigned so = min((unsigned)(k2 >> 32), vm2);
    float bv = unordf((unsigned)(k1 >> 32));
    float sv = unordf(so);
    int code = (int)(k1 & 0xFFFFFFFFu);
    codes_i[row] = code;
    codes_f[row] = (float)code;
    if (sv - bv < MARGIN) { int p = atomicAdd(cnt, 1); list[p] = row; }
}

// ---------------- K4: exact fp32 re-rank, 64 rows x 64 codes per block ----
__global__ __launch_bounds__(256)
void refine2_kernel(const float* __restrict__ z, const float* __restrict__ w,
                    const float* __restrict__ wsq,
                    const int* __restrict__ cnt, const int* __restrict__ list,
                    u64* __restrict__ exact) {
    __shared__ float zs[64][68];      // [k][row], pad 4 -> 16B-aligned rows
    __shared__ float ws[64][68];      // [k][code]
    __shared__ int rows_s[64];
    const int n  = *cnt;
    const int c0 = blockIdx.x * 64;
    const int t  = threadIdx.x;
    const int lr = t & 63, lc = t >> 6;       // staging: row/code, k-group
    const int ty = t >> 4, tx = t & 15;       // compute: 4 rows x 4 codes

    for (int row0 = blockIdx.y * 64; row0 < n; row0 += gridDim.y * 64) {
        if (t < 64) {
            int ri = row0 + t;
            rows_s[t] = list[ri < n ? ri : n - 1];   // clamp: dup work, same result
        }
        __syncthreads();
        float acc[4][4] = {};
        const int zrow = rows_s[lr];
        for (int k0 = 0; k0 < D_DIM; k0 += 64) {
            #pragma unroll
            for (int it = 0; it < 4; ++it) {
                int kc = (lc * 4 + it) * 4;           // 0..60
                float4 v = *(const float4*)(z + (size_t)zrow * D_DIM + k0 + kc);
                zs[kc+0][lr] = v.x; zs[kc+1][lr] = v.y;
                zs[kc+2][lr] = v.z; zs[kc+3][lr] = v.w;
                float4 u = *(const float4*)(w + (size_t)(c0 + lr) * D_DIM + k0 + kc);
                ws[kc+0][lr] = u.x; ws[kc+1][lr] = u.y;
                ws[kc+2][lr] = u.z; ws[kc+3][lr] = u.w;
            }
            __syncthreads();
            #pragma unroll 8
            for (int k = 0; k < 64; ++k) {
                float4 za = *(const float4*)&zs[k][ty * 4];
                float4 wa = *(const float4*)&ws[k][tx * 4];
                float zav[4] = {za.x, za.y, za.z, za.w};
                float wav[4] = {wa.x, wa.y, wa.z, wa.w};
                #pragma unroll
                for (int i = 0; i < 4; ++i)
                    #pragma unroll
                    for (int j = 0; j < 4; ++j)
                        acc[i][j] += zav[i] * wav[j];
            }
            __syncthreads();
        }
        #pragma unroll
        for (int i = 0; i < 4; ++i) {
            u64 key = ~0ull;
            #pragma unroll
            for (int j = 0; j < 4; ++j) {
                int c = c0 + tx * 4 + j;
                float d = wsq[c] - 2.0f * acc[i][j];
                u64 k = ((u64)ordf(d) << 32) | (unsigned)c;
                if (k < key) key = k;
            }
            #pragma unroll
            for (int m = 1; m <= 8; m <<= 1) {
                u64 o = __shfl_xor(key, m);
                key = o < key ? o : key;
            }
            if (tx == 0) atomicMin(exact + rows_s[ty * 4 + i], key);
        }
        __syncthreads();   // protect rows_s/zs before next row-tile
    }
}

__global__ __launch_bounds__(256)
void refine_fix_kernel(const int* __restrict__ cnt, const int* __restrict__ list,
                       const u64* __restrict__ exact,
                       int* __restrict__ codes_i, float* __restrict__ codes_f) {
    int n = *cnt;
    for (int i = blockIdx.x * 256 + threadIdx.x; i < n; i += 64 * 256) {
        int row = list[i];
        int code = (int)(exact[row] & 0xFFFFFFFFu);
        codes_i[row] = code;
        codes_f[row] = (float)code;
    }
}

// ---------------- K5: counts + dw scatter ---------------------------------
__global__ __launch_bounds__(256)
void scatter_kernel(const int* __restrict__ codes_i, const float* __restrict__ z,
                    float* __restrict__ cnt_acc, float* __restrict__ dw_acc) {
    int row = blockIdx.x * 8 + (threadIdx.x >> 5);
    int c   = threadIdx.x & 31;
    int code = codes_i[row];
    if (c == 0) atomicAdd(&cnt_acc[code], 1.0f);
    const float* zr = z + (size_t)row * D_DIM;
    float* dr = dw_acc + (size_t)code * D_DIM;
    #pragma unroll
    for (int d = c; d < D_DIM; d += 32) atomicAdd(&dr[d], zr[d]);
}

// ---------------- K6: new_cs (in-place) + nsum ----------------------------
__global__ __launch_bounds__(256)
void cs_kernel(const float* __restrict__ ema_cs, float* __restrict__ cs_out,
               float* __restrict__ nsum) {
    __shared__ float wsum[4];
    int i = blockIdx.x * 256 + threadIdx.x;
    float v = ema_cs[i] * DECAY + (1.0f - DECAY) * cs_out[i];
    cs_out[i] = v;
    float s = v;
    #pragma unroll
    for (int off = 32; off; off >>= 1) s += __shfl_down(s, off);
    int lane = threadIdx.x & 63, wid = threadIdx.x >> 6;
    if (lane == 0) wsum[wid] = s;
    __syncthreads();
    if (threadIdx.x == 0)
        atomicAdd(nsum, wsum[0] + wsum[1] + wsum[2] + wsum[3]);
}

// ---------------- K7: new_ema_w (in-place) + new_weight -------------------
__global__ __launch_bounds__(256)
void weight_kernel(const float* __restrict__ ema_w, const float* __restrict__ cs,
                   const float* __restrict__ nsum_p,
                   float* __restrict__ emaw_out, float* __restrict__ w_out) {
    int i = blockIdx.x * 256 + threadIdx.x;
    float dw = emaw_out[i];
    float ne = ema_w[i] * DECAY + (1.0f - DECAY) * dw;
    emaw_out[i] = ne;
    int k = i >> 9;
    float n = *nsum_p;
    float csize = (cs[k] + EPS_VQ) / (n + (float)K_CODES * EPS_VQ) * n;
    w_out[i] = ne / csize;
}

// ---------------- K8: z_q gather + loss -----------------------------------
__global__ __launch_bounds__(256)
void gather_loss_kernel(const float* __restrict__ z, const int* __restrict__ codes,
                        const float* __restrict__ w, float* __restrict__ zq,
                        float* __restrict__ loss_acc) {
    __shared__ float wsum[4];
    int row  = blockIdx.x * 4 + (threadIdx.x >> 6);
    int lane = threadIdx.x & 63;
    int code = codes[row];
    const float* zr = z + (size_t)row * D_DIM;
    const float* wr = w + (size_t)code * D_DIM;
    float s = 0.0f;
    #pragma unroll
    for (int d = lane; d < D_DIM; d += 64) {
        float qv = wr[d];
        float diff = qv - zr[d];
        s += diff * diff;
        zq[(size_t)row * D_DIM + d] = qv;
    }
    #pragma unroll
    for (int off = 32; off; off >>= 1) s += __shfl_down(s, off);
    int wid = threadIdx.x >> 6;
    if (lane == 0) wsum[wid] = s;
    __syncthreads();
    if (threadIdx.x == 0)
        atomicAdd(loss_acc, wsum[0] + wsum[1] + wsum[2] + wsum[3]);
}

__global__ void finalize_kernel(const float* __restrict__ loss_acc,
                                float* __restrict__ out0) {
    *out0 = COMMIT * (*loss_acc) / 16777216.0f;
}

// ---------------- launch --------------------------------------------------
extern "C" void kernel_launch(void* const* d_in, const int* in_sizes, int n_in,
                              void* d_out, int out_size, void* d_ws, size_t ws_size,
                              hipStream_t stream) {
    const float* z      = (const float*)d_in[0];
    const float* weight = (const float*)d_in[1];
    const float* ema_cs = (const float*)d_in[2];
    const float* ema_w  = (const float*)d_in[3];

    float* out       = (float*)d_out;
    float* out_loss  = out;
    float* out_zq    = out + 1;
    float* out_codes = out + 16777217;
    float* out_w     = out + 16809985;
    float* out_cs    = out + 21004289;
    float* out_emaw  = out + 21012481;

    // f16 operands in z_q region (z_q written last); partials in tail region
    half_t* A_hi = (half_t*)(out + 4);
    half_t* B_hi = (half_t*)(out + 8388612);
    uint4*  partial = (uint4*)(out + 16809988);   // 16B-aligned, 32MB

    char* ws = (char*)d_ws;
    float* wsq      = (float*)ws;                 // 32KB
    int*   codes_i  = (int*)(ws + 32768);         // 128KB
    int*   cnt      = (int*)(ws + 163840);
    float* nsum     = (float*)(ws + 163844);
    float* loss_acc = (float*)(ws + 163848);
    int*   list     = (int*)(ws + 163856);        // 128KB
    u64*   exact    = (u64*)(ws + 294928);        // 256KB

    hipMemsetAsync(cnt, 0, 16, stream);                     // cnt+nsum+loss
    hipMemsetAsync(exact, 0xFF, N_VEC * 8, stream);

    conv_half_kernel<<<N_VEC * D_DIM / 1024, 256, 0, stream>>>(z, A_hi);
    conv_half_kernel<<<K_CODES * D_DIM / 1024, 256, 0, stream>>>(weight, B_hi);
    wsq_kernel<<<K_CODES / 4, 256, 0, stream>>>(weight, wsq);

    dim3 g2(K_CODES / 128, N_VEC / 128);                    // 64 x 256
    dist1_kernel<<<g2, 256, 0, stream>>>(A_hi, B_hi, wsq, partial);

    reduce_top2_kernel<<<N_VEC / 256, 256, 0, stream>>>(partial, codes_i,
                                                        out_codes, cnt, list);

    // partials dead -> accumulators may now be zeroed
    hipMemsetAsync(out_cs, 0, 8192 * 4, stream);
    hipMemsetAsync(out_emaw, 0, (size_t)4194304 * 4, stream);

    dim3 gr(K_CODES / 64, 64);                              // 128 x 64
    refine2_kernel<<<gr, 256, 0, stream>>>(z, weight, wsq, cnt, list, exact);
    refine_fix_kernel<<<64, 256, 0, stream>>>(cnt, list, exact,
                                              codes_i, out_codes);

    scatter_kernel<<<N_VEC / 8, 256, 0, stream>>>(codes_i, z, out_cs, out_emaw);
    cs_kernel<<<K_CODES / 256, 256, 0, stream>>>(ema_cs, out_cs, nsum);
    weight_kernel<<<4194304 / 256, 256, 0, stream>>>(ema_w, out_cs, nsum,
                                                     out_emaw, out_w);
    gather_loss_kernel<<<N_VEC / 4, 256, 0, stream>>>(z, codes_i, out_w,
                                                      out_zq, loss_acc);
    finalize_kernel<<<1, 1, 0, stream>>>(loss_acc, out_loss);
}

// Round 3
// 918.675 us; speedup vs baseline: 1.0102x; 1.0102x over previous
//
#include <hip/hip_runtime.h>
#include <cstdint>

#define K_CODES 8192
#define D_DIM   512
#define N_VEC   32768          // 16*2048
#define DECAY   0.99f
#define EPS_VQ  1e-5f
#define COMMIT  0.25f
#define MARGIN  0.25f          // stage-1 f16 dist error std ~0.03 -> ~8 sigma
                               // (key clip adds <=0.016 abs, still ~7.5 sigma)

typedef _Float16 half_t;
typedef _Float16 half8 __attribute__((ext_vector_type(8)));
typedef _Float16 half4 __attribute__((ext_vector_type(4)));
typedef float    f32x4 __attribute__((ext_vector_type(4)));
typedef unsigned long long u64;

// async global->LDS DMA, 16B per lane; LDS dest must be linear in lane order
#define GL2L(g, l)                                                              \
    __builtin_amdgcn_global_load_lds(                                           \
        (const __attribute__((address_space(1))) unsigned int*)(g),             \
        (__attribute__((address_space(3))) unsigned int*)(l), 16, 0, 0)

__device__ __forceinline__ unsigned ordf(float f) {
    unsigned u = __float_as_uint(f);
    return (u & 0x80000000u) ? ~u : (u | 0x80000000u);
}
__device__ __forceinline__ float unordf(unsigned u) {
    u = (u & 0x80000000u) ? (u & 0x7FFFFFFFu) : ~u;
    return __uint_as_float(u);
}

// ---------------- output layout (float32, concatenated in return order) ---
// [0] loss | [1..16777217) z_q | [16777217..16809985) codes |
// [16809985..21004289) new_weight | [21004289..21012481) new_cs |
// [21012481..25206785) new_ema_w
//
// d_out scratch lifetimes:
//   A_hi f16 [out+4 ..)          32MB  (z_q region; z_q written last)
//   B_hi f16 [out+8388612 ..)     8MB  (z_q region)
//   partials [out+16809988 ..)   16MB  (new_weight/cs/ema_w region; dead
//                                       before those are memset/written)

// ---------------- K0: fp32 -> f16 cast ------------------------------------
__global__ __launch_bounds__(256)
void conv_half_kernel(const float* __restrict__ x, half_t* __restrict__ out) {
    int i = blockIdx.x * 256 + threadIdx.x;
    float4 v = ((const float4*)x)[i];
    half4 h = { (_Float16)v.x, (_Float16)v.y, (_Float16)v.z, (_Float16)v.w };
    *(half4*)(out + (size_t)i * 4) = h;
}

// ---------------- K1: wsq[k] = sum_d w[k][d]^2 (fp32) ---------------------
__global__ __launch_bounds__(256)
void wsq_kernel(const float* __restrict__ w, float* __restrict__ wsq) {
    int wave = threadIdx.x >> 6, lane = threadIdx.x & 63;
    int row  = blockIdx.x * 4 + wave;
    const float4* p = (const float4*)(w + (size_t)row * D_DIM);
    float4 a = p[lane], b = p[lane + 64];
    float s = a.x*a.x + a.y*a.y + a.z*a.z + a.w*a.w
            + b.x*b.x + b.y*b.y + b.z*b.z + b.w*b.w;
    #pragma unroll
    for (int off = 32; off; off >>= 1) s += __shfl_down(s, off);
    if (lane == 0) wsq[row] = s;
}

// ---------------- K2: 256x256 double-buffered f16 MFMA dist + top-2 -------
// v5: counted-vmcnt pipeline (T3/T4) at 256^2 tile.
//  * 512 thr / 8 waves (2M x 4N), per-wave 128x64 output, BK=64, D=512 ->
//    8 K-tiles, LDS 128KB = 2 x (A 32KB + B 32KB) double buffer.
//  * Loop: stage next tile (8 GL2L) -> s_waitcnt vmcnt(8) (counted; loads
//    stay in flight across RAW s_barrier, never drained in-loop) -> 64 MFMA
//    under setprio(1) -> barrier.  wsq loads sit after the loop and cannot
//    hoist across the asm-volatile waits, so vmcnt counts stay exact.
//  * 256^2 tile halves L2/L3 staging traffic vs 128^2 (4.3GB -> 2.1GB);
//    XCD-bijective swizzle keeps each A row-panel L2-resident per XCD.
//  * Keys: a' = dot - wsq/2 + 512 > 0 (needs dot < wsq/2 + 512: ~15 sigma
//    margin), key = (bits & ~255) | col8 (clip err <=0.0078 -> <=0.016 in
//    dist; ties/distortion shrink the top-2 gap -> row flagged -> exact
//    refine).  Per-wave LDS-transpose merge in two 64-row chunks (stride-17
//    u64 slots, intra-wave only), then 4-way cross-wave merge.
__global__ __launch_bounds__(512, 2)
void dist1_kernel(const half_t* __restrict__ A, const half_t* __restrict__ B,
                  const float* __restrict__ wsq, uint4* __restrict__ partial) {
    // staging: A0 @0 (32KB) | B0 @32768 | A1 @65536 | B1 @98304
    // epilogue overlay (after final barrier):
    //   per wave @ wave*8704: uint2 kp[64][17]  (8 waves -> 69632B)
    //   fm @ 69632: uint2[256][4]
    __shared__ __align__(16) char smem[131072];
    half_t* A0 = (half_t*)smem;
    half_t* B0 = (half_t*)(smem + 32768);
    half_t* A1 = (half_t*)(smem + 65536);
    half_t* B1 = (half_t*)(smem + 98304);

    // XCD-bijective swizzle: 4096 blocks, 8 XCDs, 512/XCD; within an XCD
    // x (code-block) varies fastest -> A row-panel reused 32x from its L2.
    const int wg  = blockIdx.x;
    const int swz = (wg & 7) * 512 + (wg >> 3);
    const int k0  = (swz & 31) * 256;     // codes
    const int n0  = (swz >> 5) * 256;     // z rows

    const int t    = threadIdx.x;
    const int lane = t & 63;
    const int wave = t >> 6;              // 0..7
    const int wm   = (wave >> 2) * 128;   // M quadrant (2)
    const int wn   = (wave & 3) * 64;     // N quadrant (4)
    const int l15  = lane & 15;
    const int q    = lane >> 4;

    // staging addresses: chunk idx = t + 512*i, row = idx>>3,
    // col8 = (idx&7) ^ (row&7) (XOR swizzle); LDS dest linear in lane order.
    const half_t* ga[4]; const half_t* gb[4];
    #pragma unroll
    for (int i = 0; i < 4; ++i) {
        int idx  = t + 512 * i;
        int row  = idx >> 3;
        int col8 = (idx & 7) ^ (row & 7);
        ga[i] = A + (size_t)(n0 + row) * D_DIM + col8 * 8;
        gb[i] = B + (size_t)(k0 + row) * D_DIM + col8 * 8;
    }

    f32x4 acc[8][4];
    #pragma unroll
    for (int mi = 0; mi < 8; ++mi)
        #pragma unroll
        for (int ni = 0; ni < 4; ++ni) acc[mi][ni] = (f32x4)0.0f;

    auto stage = [&](int kt, half_t* la, half_t* lb) {
        #pragma unroll
        for (int i = 0; i < 4; ++i) {
            GL2L(ga[i] + kt * 64, la + (size_t)(t + 512 * i) * 8);
            GL2L(gb[i] + kt * 64, lb + (size_t)(t + 512 * i) * 8);
        }
    };
    auto compute = [&](const half_t* la, const half_t* lb) {
        #pragma unroll
        for (int kk = 0; kk < 2; ++kk) {
            half8 af[8], bf[4];
            const int cpos = ((kk * 4 + q) ^ (l15 & 7)) * 8;   // de-swizzle
            #pragma unroll
            for (int mi = 0; mi < 8; ++mi)
                af[mi] = *(const half8*)&la[(wm + mi * 16 + l15) * 64 + cpos];
            #pragma unroll
            for (int ni = 0; ni < 4; ++ni)
                bf[ni] = *(const half8*)&lb[(wn + ni * 16 + l15) * 64 + cpos];
            __builtin_amdgcn_s_setprio(1);
            #pragma unroll
            for (int mi = 0; mi < 8; ++mi)
                #pragma unroll
                for (int ni = 0; ni < 4; ++ni)
                    acc[mi][ni] = __builtin_amdgcn_mfma_f32_16x16x32_f16(
                        af[mi], bf[ni], acc[mi][ni], 0, 0, 0);
            __builtin_amdgcn_s_setprio(0);
        }
    };

    stage(0, A0, B0);
    #pragma unroll
    for (int kt = 0; kt < 8; ++kt) {
        half_t* la = (kt & 1) ? A1 : A0;
        half_t* lb = (kt & 1) ? B1 : B0;
        if (kt < 7) {
            stage(kt + 1, (kt & 1) ? A0 : A1, (kt & 1) ? B0 : B1);
            asm volatile("s_waitcnt vmcnt(8)" ::: "memory");   // cur done,
        } else {                                               // next in flight
            asm volatile("s_waitcnt vmcnt(0)" ::: "memory");
        }
        __builtin_amdgcn_s_barrier();
        compute(la, lb);
        __builtin_amdgcn_s_barrier();   // all reads done before next stage
    }

    // -------- epilogue: top-2 per row over this block's 256 codes --------
    uint2* kp  = (uint2*)(smem + wave * 8704);       // [64][17] per wave
    uint2* fmp = (uint2*)(smem + 69632);             // [256][4]

    float wb[4]; unsigned cb[4];
    #pragma unroll
    for (int ni = 0; ni < 4; ++ni) {
        wb[ni] = 512.0f - 0.5f * wsq[k0 + wn + ni * 16 + l15];
        cb[ni] = (unsigned)(wn + ni * 16 + l15);     // 0..255
    }

    uint2 res[2];
    #pragma unroll
    for (int half = 0; half < 2; ++half) {
        // phase 1: per-lane top-2 keys over its 4 cols, stash transposed
        #pragma unroll
        for (int mi2 = 0; mi2 < 4; ++mi2) {
            const int mi = half * 4 + mi2;
            #pragma unroll
            for (int r = 0; r < 4; ++r) {
                unsigned k1 = 0u, k2 = 0u;
                #pragma unroll
                for (int ni = 0; ni < 4; ++ni) {
                    float a = acc[mi][ni][r] + wb[ni];
                    unsigned key = (__float_as_uint(a) & 0xFFFFFF00u) | cb[ni];
                    unsigned lo = min(k1, key);
                    k1 = max(k1, key);
                    k2 = max(k2, lo);
                }
                int row = mi2 * 16 + q * 4 + r;      // 0..63 in chunk
                kp[row * 17 + l15] = make_uint2(k1, k2);
            }
        }
        // phase 2: lane owns chunk row == lane; serial 16-way merge
        // (intra-wave only: lockstep issue + compiler lgkm ordering)
        const int rb = lane * 17;
        uint2 e0 = kp[rb];
        unsigned W1 = e0.x, W2 = e0.y;
        #pragma unroll
        for (int j = 1; j < 16; ++j) {
            uint2 e = kp[rb + j];
            unsigned lo = min(W1, e.x);
            W1 = max(W1, e.x);
            W2 = max(max(W2, lo), e.y);              // v_max3_u32
        }
        res[half] = make_uint2(W1, W2);
    }
    fmp[(wm + lane) * 4 + (wave & 3)]      = res[0];
    fmp[(wm + 64 + lane) * 4 + (wave & 3)] = res[1];
    asm volatile("s_waitcnt lgkmcnt(0)" ::: "memory");
    __builtin_amdgcn_s_barrier();

    // phase 3: merge the 4 N-wave strips, pack partial
    if (t < 256) {
        uint2 a = fmp[t * 4 + 0], b = fmp[t * 4 + 1];
        uint2 c = fmp[t * 4 + 2], d = fmp[t * 4 + 3];
        unsigned mab = max(a.x, b.x), mcd = max(c.x, d.x);
        unsigned sab = min(a.x, b.x), scd = min(c.x, d.x);
        unsigned W1 = max(mab, mcd);
        unsigned sec1 = max(min(mab, mcd), max(sab, scd)); // 2nd of the k1s
        unsigned W2 = max(max(max(a.y, b.y), max(c.y, d.y)), sec1);
        unsigned col = (unsigned)k0 + (W1 & 255u);
        float v1 = __uint_as_float(W1 & 0xFFFFFF00u);
        float v2 = __uint_as_float(W2 & 0xFFFFFF00u);
        float d1 = 1024.0f - 2.0f * v1;              // dist = -2*(a'-512)
        float d2 = 1024.0f - 2.0f * v2;
        partial[(size_t)(swz & 31) * N_VEC + n0 + t] =
            make_uint4(col, ordf(d1), ordf(d2), 0u);
    }
}

// ---------------- K3: merge 32 partials/row, flag ambiguous rows ----------
__global__ __launch_bounds__(256)
void reduce_top2_kernel(const uint4* __restrict__ partial,
                        int* __restrict__ codes_i, float* __restrict__ codes_f,
                        int* __restrict__ cnt, int* __restrict__ list) {
    int row = blockIdx.x * 256 + threadIdx.x;
    u64 k1 = ~0ull, k2 = ~0ull;
    unsigned vm2 = 0xFFFFFFFFu;
    for (int kb = 0; kb < 32; ++kb) {
        uint4 e = partial[(size_t)kb * N_VEC + row];
        u64 k = ((u64)e.y << 32) | e.x;
        if (k < k1) { k2 = k1; k1 = k; }
        else if (k < k2) k2 = k;
        vm2 = min(vm2, e.z);
    }
    unsigned so = min((unsigned)(k2 >> 32), vm2);
    float bv = unordf((unsigned)(k1 >> 32));
    float sv = unordf(so);
    int code = (int)(k1 & 0xFFFFFFFFu);
    codes_i[row] = code;
    codes_f[row] = (float)code;
    if (sv - bv < MARGIN) { int p = atomicAdd(cnt, 1); list[p] = row; }
}

// ---------------- K4: exact fp32 re-rank, 64 rows x 64 codes per block ----
__global__ __launch_bounds__(256)
void refine2_kernel(const float* __restrict__ z, const float* __restrict__ w,
                    const float* __restrict__ wsq,
                    const int* __restrict__ cnt, const int* __restrict__ list,
                    u64* __restrict__ exact) {
    __shared__ float zs[64][68];      // [k][row], pad 4 -> 16B-aligned rows
    __shared__ float ws[64][68];      // [k][code]
    __shared__ int rows_s[64];
    const int n  = *cnt;
    const int c0 = blockIdx.x * 64;
    const int t  = threadIdx.x;
    const int lr = t & 63, lc = t >> 6;       // staging: row/code, k-group
    const int ty = t >> 4, tx = t & 15;       // compute: 4 rows x 4 codes

    for (int row0 = blockIdx.y * 64; row0 < n; row0 += gridDim.y * 64) {
        if (t < 64) {
            int ri = row0 + t;
            rows_s[t] = list[ri < n ? ri : n - 1];   // clamp: dup work, same result
        }
        __syncthreads();
        float acc[4][4] = {};
        const int zrow = rows_s[lr];
        for (int k0 = 0; k0 < D_DIM; k0 += 64) {
            #pragma unroll
            for (int it = 0; it < 4; ++it) {
                int kc = (lc * 4 + it) * 4;           // 0..60
                float4 v = *(const float4*)(z + (size_t)zrow * D_DIM + k0 + kc);
                zs[kc+0][lr] = v.x; zs[kc+1][lr] = v.y;
                zs[kc+2][lr] = v.z; zs[kc+3][lr] = v.w;
                float4 u = *(const float4*)(w + (size_t)(c0 + lr) * D_DIM + k0 + kc);
                ws[kc+0][lr] = u.x; ws[kc+1][lr] = u.y;
                ws[kc+2][lr] = u.z; ws[kc+3][lr] = u.w;
            }
            __syncthreads();
            #pragma unroll 8
            for (int k = 0; k < 64; ++k) {
                float4 za = *(const float4*)&zs[k][ty * 4];
                float4 wa = *(const float4*)&ws[k][tx * 4];
                float zav[4] = {za.x, za.y, za.z, za.w};
                float wav[4] = {wa.x, wa.y, wa.z, wa.w};
                #pragma unroll
                for (int i = 0; i < 4; ++i)
                    #pragma unroll
                    for (int j = 0; j < 4; ++j)
                        acc[i][j] += zav[i] * wav[j];
            }
            __syncthreads();
        }
        #pragma unroll
        for (int i = 0; i < 4; ++i) {
            u64 key = ~0ull;
            #pragma unroll
            for (int j = 0; j < 4; ++j) {
                int c = c0 + tx * 4 + j;
                float d = wsq[c] - 2.0f * acc[i][j];
                u64 k = ((u64)ordf(d) << 32) | (unsigned)c;
                if (k < key) key = k;
            }
            #pragma unroll
            for (int m = 1; m <= 8; m <<= 1) {
                u64 o = __shfl_xor(key, m);
                key = o < key ? o : key;
            }
            if (tx == 0) atomicMin(exact + rows_s[ty * 4 + i], key);
        }
        __syncthreads();   // protect rows_s/zs before next row-tile
    }
}

__global__ __launch_bounds__(256)
void refine_fix_kernel(const int* __restrict__ cnt, const int* __restrict__ list,
                       const u64* __restrict__ exact,
                       int* __restrict__ codes_i, float* __restrict__ codes_f) {
    int n = *cnt;
    for (int i = blockIdx.x * 256 + threadIdx.x; i < n; i += 64 * 256) {
        int row = list[i];
        int code = (int)(exact[row] & 0xFFFFFFFFu);
        codes_i[row] = code;
        codes_f[row] = (float)code;
    }
}

// ---------------- K5: counts + dw scatter ---------------------------------
__global__ __launch_bounds__(256)
void scatter_kernel(const int* __restrict__ codes_i, const float* __restrict__ z,
                    float* __restrict__ cnt_acc, float* __restrict__ dw_acc) {
    int row = blockIdx.x * 8 + (threadIdx.x >> 5);
    int c   = threadIdx.x & 31;
    int code = codes_i[row];
    if (c == 0) atomicAdd(&cnt_acc[code], 1.0f);
    const float* zr = z + (size_t)row * D_DIM;
    float* dr = dw_acc + (size_t)code * D_DIM;
    #pragma unroll
    for (int d = c; d < D_DIM; d += 32) atomicAdd(&dr[d], zr[d]);
}

// ---------------- K6: new_cs (in-place) + nsum ----------------------------
__global__ __launch_bounds__(256)
void cs_kernel(const float* __restrict__ ema_cs, float* __restrict__ cs_out,
               float* __restrict__ nsum) {
    __shared__ float wsum[4];
    int i = blockIdx.x * 256 + threadIdx.x;
    float v = ema_cs[i] * DECAY + (1.0f - DECAY) * cs_out[i];
    cs_out[i] = v;
    float s = v;
    #pragma unroll
    for (int off = 32; off; off >>= 1) s += __shfl_down(s, off);
    int lane = threadIdx.x & 63, wid = threadIdx.x >> 6;
    if (lane == 0) wsum[wid] = s;
    __syncthreads();
    if (threadIdx.x == 0)
        atomicAdd(nsum, wsum[0] + wsum[1] + wsum[2] + wsum[3]);
}

// ---------------- K7: new_ema_w (in-place) + new_weight -------------------
__global__ __launch_bounds__(256)
void weight_kernel(const float* __restrict__ ema_w, const float* __restrict__ cs,
                   const float* __restrict__ nsum_p,
                   float* __restrict__ emaw_out, float* __restrict__ w_out) {
    int i = blockIdx.x * 256 + threadIdx.x;
    float dw = emaw_out[i];
    float ne = ema_w[i] * DECAY + (1.0f - DECAY) * dw;
    emaw_out[i] = ne;
    int k = i >> 9;
    float n = *nsum_p;
    float csize = (cs[k] + EPS_VQ) / (n + (float)K_CODES * EPS_VQ) * n;
    w_out[i] = ne / csize;
}

// ---------------- K8: z_q gather + loss -----------------------------------
__global__ __launch_bounds__(256)
void gather_loss_kernel(const float* __restrict__ z, const int* __restrict__ codes,
                        const float* __restrict__ w, float* __restrict__ zq,
                        float* __restrict__ loss_acc) {
    __shared__ float wsum[4];
    int row  = blockIdx.x * 4 + (threadIdx.x >> 6);
    int lane = threadIdx.x & 63;
    int code = codes[row];
    const float* zr = z + (size_t)row * D_DIM;
    const float* wr = w + (size_t)code * D_DIM;
    float s = 0.0f;
    #pragma unroll
    for (int d = lane; d < D_DIM; d += 64) {
        float qv = wr[d];
        float diff = qv - zr[d];
        s += diff * diff;
        zq[(size_t)row * D_DIM + d] = qv;
    }
    #pragma unroll
    for (int off = 32; off; off >>= 1) s += __shfl_down(s, off);
    int wid = threadIdx.x >> 6;
    if (lane == 0) wsum[wid] = s;
    __syncthreads();
    if (threadIdx.x == 0)
        atomicAdd(loss_acc, wsum[0] + wsum[1] + wsum[2] + wsum[3]);
}

__global__ void finalize_kernel(const float* __restrict__ loss_acc,
                                float* __restrict__ out0) {
    *out0 = COMMIT * (*loss_acc) / 16777216.0f;
}

// ---------------- launch --------------------------------------------------
extern "C" void kernel_launch(void* const* d_in, const int* in_sizes, int n_in,
                              void* d_out, int out_size, void* d_ws, size_t ws_size,
                              hipStream_t stream) {
    const float* z      = (const float*)d_in[0];
    const float* weight = (const float*)d_in[1];
    const float* ema_cs = (const float*)d_in[2];
    const float* ema_w  = (const float*)d_in[3];

    float* out       = (float*)d_out;
    float* out_loss  = out;
    float* out_zq    = out + 1;
    float* out_codes = out + 16777217;
    float* out_w     = out + 16809985;
    float* out_cs    = out + 21004289;
    float* out_emaw  = out + 21012481;

    // f16 operands in z_q region (z_q written last); partials in tail region
    half_t* A_hi = (half_t*)(out + 4);
    half_t* B_hi = (half_t*)(out + 8388612);
    uint4*  partial = (uint4*)(out + 16809988);   // 16B-aligned, 16MB used

    char* ws = (char*)d_ws;
    float* wsq      = (float*)ws;                 // 32KB
    int*   codes_i  = (int*)(ws + 32768);         // 128KB
    int*   cnt      = (int*)(ws + 163840);
    float* nsum     = (float*)(ws + 163844);
    float* loss_acc = (float*)(ws + 163848);
    int*   list     = (int*)(ws + 163856);        // 128KB
    u64*   exact    = (u64*)(ws + 294928);        // 256KB

    hipMemsetAsync(cnt, 0, 16, stream);                     // cnt+nsum+loss
    hipMemsetAsync(exact, 0xFF, N_VEC * 8, stream);

    conv_half_kernel<<<N_VEC * D_DIM / 1024, 256, 0, stream>>>(z, A_hi);
    conv_half_kernel<<<K_CODES * D_DIM / 1024, 256, 0, stream>>>(weight, B_hi);
    wsq_kernel<<<K_CODES / 4, 256, 0, stream>>>(weight, wsq);

    dist1_kernel<<<4096, 512, 0, stream>>>(A_hi, B_hi, wsq, partial);

    reduce_top2_kernel<<<N_VEC / 256, 256, 0, stream>>>(partial, codes_i,
                                                        out_codes, cnt, list);

    // partials dead -> accumulators may now be zeroed
    hipMemsetAsync(out_cs, 0, 8192 * 4, stream);
    hipMemsetAsync(out_emaw, 0, (size_t)4194304 * 4, stream);

    dim3 gr(K_CODES / 64, 64);                              // 128 x 64
    refine2_kernel<<<gr, 256, 0, stream>>>(z, weight, wsq, cnt, list, exact);
    refine_fix_kernel<<<64, 256, 0, stream>>>(cnt, list, exact,
                                              codes_i, out_codes);

    scatter_kernel<<<N_VEC / 8, 256, 0, stream>>>(codes_i, z, out_cs, out_emaw);
    cs_kernel<<<K_CODES / 256, 256, 0, stream>>>(ema_cs, out_cs, nsum);
    weight_kernel<<<4194304 / 256, 256, 0, stream>>>(ema_w, out_cs, nsum,
                                                     out_emaw, out_w);
    gather_loss_kernel<<<N_VEC / 4, 256, 0, stream>>>(z, codes_i, out_w,
                                                      out_zq, loss_acc);
    finalize_kernel<<<1, 1, 0, stream>>>(loss_acc, out_loss);
}

// Round 5
// 908.355 us; speedup vs baseline: 1.0217x; 1.0114x over previous
//
#include <hip/hip_runtime.h>
#include <cstdint>

#define K_CODES 8192
#define D_DIM   512
#define N_VEC   32768          // 16*2048
#define DECAY   0.99f
#define EPS_VQ  1e-5f
#define COMMIT  0.25f
#define MARGIN  0.25f          // stage-1 f16 dist error std ~0.03 -> ~8 sigma
                               // (key clip adds <=0.016 abs, still ~7.5 sigma)

typedef _Float16 half_t;
typedef _Float16 half8 __attribute__((ext_vector_type(8)));
typedef _Float16 half4 __attribute__((ext_vector_type(4)));
typedef float    f32x4 __attribute__((ext_vector_type(4)));
typedef unsigned long long u64;

// async global->LDS DMA, 16B per lane; LDS dest must be linear in lane order
#define GL2L(g, l)                                                              \
    __builtin_amdgcn_global_load_lds(                                           \
        (const __attribute__((address_space(1))) unsigned int*)(g),             \
        (__attribute__((address_space(3))) unsigned int*)(l), 16, 0, 0)

__device__ __forceinline__ unsigned ordf(float f) {
    unsigned u = __float_as_uint(f);
    return (u & 0x80000000u) ? ~u : (u | 0x80000000u);
}
__device__ __forceinline__ float unordf(unsigned u) {
    u = (u & 0x80000000u) ? (u & 0x7FFFFFFFu) : ~u;
    return __uint_as_float(u);
}

// ---------------- output layout (float32, concatenated in return order) ---
// [0] loss | [1..16777217) z_q | [16777217..16809985) codes |
// [16809985..21004289) new_weight | [21004289..21012481) new_cs |
// [21012481..25206785) new_ema_w
//
// d_out scratch lifetimes:
//   A_hi f16 [out+4 ..)          32MB  (z_q region; z_q written last)
//   B_hi f16 [out+8388612 ..)     8MB  (z_q region)
//   partials [out+16809988 ..)   16MB  (new_weight/cs/ema_w region; dead
//                                       before those are memset/written)

// ---------------- K0: fp32 -> f16 cast (z) --------------------------------
__global__ __launch_bounds__(256)
void conv_half_kernel(const float* __restrict__ x, half_t* __restrict__ out) {
    int i = blockIdx.x * 256 + threadIdx.x;
    float4 v = ((const float4*)x)[i];
    half4 h = { (_Float16)v.x, (_Float16)v.y, (_Float16)v.z, (_Float16)v.w };
    *(half4*)(out + (size_t)i * 4) = h;
}

// ---------------- K1: weight -> f16 + wsq in one pass ---------------------
__global__ __launch_bounds__(256)
void prep_w_kernel(const float* __restrict__ w, half_t* __restrict__ wh,
                   float* __restrict__ wsq) {
    int wave = threadIdx.x >> 6, lane = threadIdx.x & 63;
    int row  = blockIdx.x * 4 + wave;
    const float4* p = (const float4*)(w + (size_t)row * D_DIM);
    float4 a = p[lane], b = p[lane + 64];
    half4 ha = { (_Float16)a.x, (_Float16)a.y, (_Float16)a.z, (_Float16)a.w };
    half4 hb = { (_Float16)b.x, (_Float16)b.y, (_Float16)b.z, (_Float16)b.w };
    *(half4*)(wh + (size_t)row * D_DIM + lane * 4)       = ha;
    *(half4*)(wh + (size_t)row * D_DIM + 256 + lane * 4) = hb;
    float s = a.x*a.x + a.y*a.y + a.z*a.z + a.w*a.w
            + b.x*b.x + b.y*b.y + b.z*b.z + b.w*b.w;
    #pragma unroll
    for (int off = 32; off; off >>= 1) s += __shfl_down(s, off);
    if (lane == 0) wsq[row] = s;
}

// ---------------- K2: 256x256 8-phase f16 MFMA dist + top-2 ---------------
// v6b: fine-grained 8-phase/2-K-tile schedule (T2+T3+T4+T5); hardened
// rebuild of v6 (builtin s_barrier; rolled pair-loop + peeled tail).
//  * Half-tiles are K-SPLIT: {A,B} x {kk0,kk1}, each 256 rows x 32 f16
//    (16KB), double-parity buffered (LDS 8 x 16KB = 128KB).  Phase
//    p = (kk, mi-half) consumes only its kk half -> each half-tile's read
//    window is 2 phases, so parity-alternating prefetch is WAR-safe.
//  * Per phase: {4x af ds_read_b128 (+4x bf at kk start, held in regs) |
//    issue ONE half-tile stage (2 GL2L) -> s_barrier -> setprio(1),
//    16 MFMA, setprio(0) -> [vmcnt(4) at phases 1,3 only] -> s_barrier}.
//    Ledger: end-of-p1 vmcnt(4) leaves newest 2 stages in flight ->
//    A1,B1(t) (staged t-1.p2/p3) complete before p2 reads; end-of-p3
//    vmcnt(4) -> A0,B0(t+1) complete before t+1.p0.  vmcnt-then-barrier
//    makes the guarantee collective.  Never drained to 0 in-loop.
//  * Swizzle both-sides (rule 21): stage source chunk cg = c4 ^ ((row>>1)&3)
//    with linear GL2L dest; read chunk pos = q ^ ((l15>>1)&3) (lane-const;
//    (row>>1)&3 == (l15>>1)&3 since wm, mi*16 are multiples of 16).
//  * Keys: a' = dot - wsq/2 + 512 > 0, key = (bits & ~255) | col8 (clip
//    err <= 0.016 in dist << MARGIN; distortion shrinks gap -> flagged ->
//    exact refine).
__global__ __launch_bounds__(512, 2)
void dist1_kernel(const half_t* __restrict__ A, const half_t* __restrict__ B,
                  const float* __restrict__ wsq, uint4* __restrict__ partial) {
    // slots: parity P @ P*65536; A-kh @ +kh*16384; B-kh @ +32768+kh*16384
    // epilogue overlay (after final barrier):
    //   per wave @ wave*8704: uint2 kp[64][17]; fm @ 69632: uint2[256][4]
    __shared__ __align__(16) char smem[131072];

    const int wg  = blockIdx.x;
    const int swz = (wg & 7) * 512 + (wg >> 3);   // XCD-bijective (4096%8==0)
    const int k0  = (swz & 31) * 256;             // codes
    const int n0  = (swz >> 5) * 256;             // z rows

    const int t    = threadIdx.x;
    const int lane = t & 63;
    const int wave = t >> 6;              // 0..7
    const int wm   = (wave >> 2) * 128;   // M half
    const int wn   = (wave & 3) * 64;     // N quadrant
    const int l15  = lane & 15;
    const int q    = lane >> 4;
    const int pos  = q ^ ((l15 >> 1) & 3);        // de-swizzle chunk (lane-const)

    // staging sources: 2 chunks/thread/half-tile; idx = t + 512*i,
    // row = idx>>2, c4 = idx&3, global chunk cg = c4 ^ ((row>>1)&3)
    const half_t* gsrcA[2]; const half_t* gsrcB[2]; int dsto[2];
    #pragma unroll
    for (int i = 0; i < 2; ++i) {
        int idx = t + 512 * i;
        int row = idx >> 2;
        int cg  = (idx & 3) ^ ((row >> 1) & 3);
        gsrcA[i] = A + (size_t)(n0 + row) * D_DIM + cg * 8;
        gsrcB[i] = B + (size_t)(k0 + row) * D_DIM + cg * 8;
        dsto[i]  = idx * 8;               // halfs, linear in lane order
    }

#define STAGE(isB, kh, Pdst, ktgt) do {                                      \
    half_t* _d = (half_t*)(smem + ((Pdst) * 65536) +                         \
                           ((isB) * 32768) + ((kh) * 16384));                \
    GL2L(((isB) ? gsrcB[0] : gsrcA[0]) + (ktgt) * 64 + (kh) * 32,            \
         _d + dsto[0]);                                                      \
    GL2L(((isB) ? gsrcB[1] : gsrcA[1]) + (ktgt) * 64 + (kh) * 32,            \
         _d + dsto[1]);                                                      \
  } while (0)

    const int afb = (wm + l15) * 32 + pos * 8;    // + mi*512 halfs
    const int bfb = (wn + l15) * 32 + pos * 8;    // + ni*512 halfs

#define LDAF(P, kh, mih) do {                                                \
    const half_t* _s = (const half_t*)(smem + (P) * 65536 + (kh) * 16384);   \
    af[0] = *(const half8*)&_s[afb + ((mih) * 4 + 0) * 512];                 \
    af[1] = *(const half8*)&_s[afb + ((mih) * 4 + 1) * 512];                 \
    af[2] = *(const half8*)&_s[afb + ((mih) * 4 + 2) * 512];                 \
    af[3] = *(const half8*)&_s[afb + ((mih) * 4 + 3) * 512];                 \
  } while (0)

#define LDBF(P, kh) do {                                                     \
    const half_t* _s = (const half_t*)(smem + (P) * 65536 + 32768 +          \
                                       (kh) * 16384);                        \
    bf[0] = *(const half8*)&_s[bfb + 0 * 512];                               \
    bf[1] = *(const half8*)&_s[bfb + 1 * 512];                               \
    bf[2] = *(const half8*)&_s[bfb + 2 * 512];                               \
    bf[3] = *(const half8*)&_s[bfb + 3 * 512];                               \
  } while (0)

#define MFMA16(mih) do {                                                     \
    __builtin_amdgcn_s_setprio(1);                                           \
    _Pragma("unroll")                                                        \
    for (int _j = 0; _j < 4; ++_j)                                           \
        _Pragma("unroll")                                                    \
        for (int _n = 0; _n < 4; ++_n)                                       \
            acc[(mih) * 4 + _j][_n] = __builtin_amdgcn_mfma_f32_16x16x32_f16(\
                af[_j], bf[_n], acc[(mih) * 4 + _j][_n], 0, 0, 0);           \
    __builtin_amdgcn_s_setprio(0);                                           \
  } while (0)

#define BAR()  __builtin_amdgcn_s_barrier()
#define VMC(N) asm volatile("s_waitcnt vmcnt(" #N ")" ::: "memory")

// one K-tile (4 phases).  P: parity read (literal).  STG: stage tile ktgt
// into parity 1-P.  LAST: drain fully at phase 1 (no further stages).
#define TILE(P, ktgt, STG, LAST) do {                                        \
    half8 af[4], bf[4];                                                      \
    /* phase 0: kk0, mi 0-3 (+ stage A0(ktgt)) */                            \
    LDAF(P, 0, 0); LDBF(P, 0);                                               \
    if (STG) STAGE(0, 0, 1 - (P), ktgt);                                     \
    BAR();                                                                   \
    MFMA16(0);                                                               \
    BAR();                                                                   \
    /* phase 1: kk0, mi 4-7 (+ stage B0(ktgt)) */                            \
    LDAF(P, 0, 1);                                                           \
    if (STG) STAGE(1, 0, 1 - (P), ktgt);                                     \
    BAR();                                                                   \
    MFMA16(1);                                                               \
    if (STG)       VMC(4);                                                   \
    else if (LAST) VMC(0);                                                   \
    BAR();                                                                   \
    /* phase 2: kk1, mi 0-3 (+ stage A1(ktgt)) */                            \
    LDAF(P, 1, 0); LDBF(P, 1);                                               \
    if (STG) STAGE(0, 1, 1 - (P), ktgt);                                     \
    BAR();                                                                   \
    MFMA16(0);                                                               \
    BAR();                                                                   \
    /* phase 3: kk1, mi 4-7 (+ stage B1(ktgt)) */                            \
    LDAF(P, 1, 1);                                                           \
    if (STG) STAGE(1, 1, 1 - (P), ktgt);                                     \
    BAR();                                                                   \
    MFMA16(1);                                                               \
    if (STG) VMC(4);                                                         \
    BAR();                                                                   \
  } while (0)

    f32x4 acc[8][4];
    #pragma unroll
    for (int mi = 0; mi < 8; ++mi)
        #pragma unroll
        for (int ni = 0; ni < 4; ++ni) acc[mi][ni] = (f32x4)0.0f;

    // prologue: full K-tile 0 into parity 0; wait first 2 half-tiles
    STAGE(0, 0, 0, 0); STAGE(1, 0, 0, 0); STAGE(0, 1, 0, 0); STAGE(1, 1, 0, 0);
    VMC(4);
    BAR();

    #pragma unroll 1
    for (int kt = 0; kt < 6; kt += 2) {
        TILE(0, kt + 1, true, false);
        TILE(1, kt + 2, true, false);
    }
    TILE(0, 7, true,  false);       // tile 6, stages tile 7
    TILE(1, 0, false, true);        // tile 7, no stage, drains vmcnt

#undef STAGE
#undef LDAF
#undef LDBF
#undef MFMA16
#undef BAR
#undef VMC
#undef TILE

    // -------- epilogue: top-2 per row over this block's 256 codes --------
    // (no GL2L in flight: last tile staged nothing and drained vmcnt(0))
    uint2* kp  = (uint2*)(smem + wave * 8704);       // [64][17] per wave
    uint2* fmp = (uint2*)(smem + 69632);             // [256][4]

    float wb[4]; unsigned cb[4];
    #pragma unroll
    for (int ni = 0; ni < 4; ++ni) {
        wb[ni] = 512.0f - 0.5f * wsq[k0 + wn + ni * 16 + l15];
        cb[ni] = (unsigned)(wn + ni * 16 + l15);     // 0..255
    }

    uint2 res[2];
    #pragma unroll
    for (int half = 0; half < 2; ++half) {
        // phase 1: per-lane top-2 keys over its 4 cols, stash transposed
        #pragma unroll
        for (int mi2 = 0; mi2 < 4; ++mi2) {
            const int mi = half * 4 + mi2;
            #pragma unroll
            for (int r = 0; r < 4; ++r) {
                unsigned k1 = 0u, k2 = 0u;
                #pragma unroll
                for (int ni = 0; ni < 4; ++ni) {
                    float a = acc[mi][ni][r] + wb[ni];
                    unsigned key = (__float_as_uint(a) & 0xFFFFFF00u) | cb[ni];
                    unsigned lo = min(k1, key);
                    k1 = max(k1, key);
                    k2 = max(k2, lo);
                }
                int row = mi2 * 16 + q * 4 + r;      // 0..63 in chunk
                kp[row * 17 + l15] = make_uint2(k1, k2);
            }
        }
        // phase 2: lane owns chunk row == lane; serial 16-way merge
        // (intra-wave only: DS ops of one wave complete in order)
        const int rb = lane * 17;
        uint2 e0 = kp[rb];
        unsigned W1 = e0.x, W2 = e0.y;
        #pragma unroll
        for (int j = 1; j < 16; ++j) {
            uint2 e = kp[rb + j];
            unsigned lo = min(W1, e.x);
            W1 = max(W1, e.x);
            W2 = max(max(W2, lo), e.y);              // v_max3_u32
        }
        res[half] = make_uint2(W1, W2);
    }
    fmp[(wm + lane) * 4 + (wave & 3)]      = res[0];
    fmp[(wm + 64 + lane) * 4 + (wave & 3)] = res[1];
    __syncthreads();

    // phase 3: merge the 4 N-wave strips, pack partial
    if (t < 256) {
        uint2 a = fmp[t * 4 + 0], b = fmp[t * 4 + 1];
        uint2 c = fmp[t * 4 + 2], d = fmp[t * 4 + 3];
        unsigned mab = max(a.x, b.x), mcd = max(c.x, d.x);
        unsigned sab = min(a.x, b.x), scd = min(c.x, d.x);
        unsigned W1 = max(mab, mcd);
        unsigned sec1 = max(min(mab, mcd), max(sab, scd)); // 2nd of the k1s
        unsigned W2 = max(max(max(a.y, b.y), max(c.y, d.y)), sec1);
        unsigned col = (unsigned)k0 + (W1 & 255u);
        float v1 = __uint_as_float(W1 & 0xFFFFFF00u);
        float v2 = __uint_as_float(W2 & 0xFFFFFF00u);
        float d1 = 1024.0f - 2.0f * v1;              // dist = -2*(a'-512)
        float d2 = 1024.0f - 2.0f * v2;
        partial[(size_t)(swz & 31) * N_VEC + n0 + t] =
            make_uint4(col, ordf(d1), ordf(d2), 0u);
    }
}

// ---------------- K3: merge 32 partials/row, flag ambiguous rows ----------
__global__ __launch_bounds__(256)
void reduce_top2_kernel(const uint4* __restrict__ partial,
                        int* __restrict__ codes_i, float* __restrict__ codes_f,
                        int* __restrict__ cnt, int* __restrict__ list) {
    int row = blockIdx.x * 256 + threadIdx.x;
    u64 k1 = ~0ull, k2 = ~0ull;
    unsigned vm2 = 0xFFFFFFFFu;
    for (int kb = 0; kb < 32; ++kb) {
        uint4 e = partial[(size_t)kb * N_VEC + row];
        u64 k = ((u64)e.y << 32) | e.x;
        if (k < k1) { k2 = k1; k1 = k; }
        else if (k < k2) k2 = k;
        vm2 = min(vm2, e.z);
    }
    unsigned so = min((unsigned)(k2 >> 32), vm2);
    float bv = unordf((unsigned)(k1 >> 32));
    float sv = unordf(so);
    int code = (int)(k1 & 0xFFFFFFFFu);
    codes_i[row] = code;
    codes_f[row] = (float)code;
    if (sv - bv < MARGIN) { int p = atomicAdd(cnt, 1); list[p] = row; }
}

// ---------------- K4: exact fp32 re-rank, 64 rows x 64 codes per block ----
__global__ __launch_bounds__(256)
void refine2_kernel(const float* __restrict__ z, const float* __restrict__ w,
                    const float* __restrict__ wsq,
                    const int* __restrict__ cnt, const int* __restrict__ list,
                    u64* __restrict__ exact) {
    __shared__ float zs[64][68];      // [k][row], pad 4 -> 16B-aligned rows
    __shared__ float ws[64][68];      // [k][code]
    __shared__ int rows_s[64];
    const int n  = *cnt;
    const int c0 = blockIdx.x * 64;
    const int t  = threadIdx.x;
    const int lr = t & 63, lc = t >> 6;       // staging: row/code, k-group
    const int ty = t >> 4, tx = t & 15;       // compute: 4 rows x 4 codes

    for (int row0 = blockIdx.y * 64; row0 < n; row0 += gridDim.y * 64) {
        if (t < 64) {
            int ri = row0 + t;
            rows_s[t] = list[ri < n ? ri : n - 1];   // clamp: dup work, same result
        }
        __syncthreads();
        float acc[4][4] = {};
        const int zrow = rows_s[lr];
        for (int k0 = 0; k0 < D_DIM; k0 += 64) {
            #pragma unroll
            for (int it = 0; it < 4; ++it) {
                int kc = (lc * 4 + it) * 4;           // 0..60
                float4 v = *(const float4*)(z + (size_t)zrow * D_DIM + k0 + kc);
                zs[kc+0][lr] = v.x; zs[kc+1][lr] = v.y;
                zs[kc+2][lr] = v.z; zs[kc+3][lr] = v.w;
                float4 u = *(const float4*)(w + (size_t)(c0 + lr) * D_DIM + k0 + kc);
                ws[kc+0][lr] = u.x; ws[kc+1][lr] = u.y;
                ws[kc+2][lr] = u.z; ws[kc+3][lr] = u.w;
            }
            __syncthreads();
            #pragma unroll 8
            for (int k = 0; k < 64; ++k) {
                float4 za = *(const float4*)&zs[k][ty * 4];
                float4 wa = *(const float4*)&ws[k][tx * 4];
                float zav[4] = {za.x, za.y, za.z, za.w};
                float wav[4] = {wa.x, wa.y, wa.z, wa.w};
                #pragma unroll
                for (int i = 0; i < 4; ++i)
                    #pragma unroll
                    for (int j = 0; j < 4; ++j)
                        acc[i][j] += zav[i] * wav[j];
            }
            __syncthreads();
        }
        #pragma unroll
        for (int i = 0; i < 4; ++i) {
            u64 key = ~0ull;
            #pragma unroll
            for (int j = 0; j < 4; ++j) {
                int c = c0 + tx * 4 + j;
                float d = wsq[c] - 2.0f * acc[i][j];
                u64 k = ((u64)ordf(d) << 32) | (unsigned)c;
                if (k < key) key = k;
            }
            #pragma unroll
            for (int m = 1; m <= 8; m <<= 1) {
                u64 o = __shfl_xor(key, m);
                key = o < key ? o : key;
            }
            if (tx == 0) atomicMin(exact + rows_s[ty * 4 + i], key);
        }
        __syncthreads();   // protect rows_s/zs before next row-tile
    }
}

__global__ __launch_bounds__(256)
void refine_fix_kernel(const int* __restrict__ cnt, const int* __restrict__ list,
                       const u64* __restrict__ exact,
                       int* __restrict__ codes_i, float* __restrict__ codes_f) {
    int n = *cnt;
    for (int i = blockIdx.x * 256 + threadIdx.x; i < n; i += 64 * 256) {
        int row = list[i];
        int code = (int)(exact[row] & 0xFFFFFFFFu);
        codes_i[row] = code;
        codes_f[row] = (float)code;
    }
}

// ---------------- K5: counts + dw scatter ---------------------------------
__global__ __launch_bounds__(256)
void scatter_kernel(const int* __restrict__ codes_i, const float* __restrict__ z,
                    float* __restrict__ cnt_acc, float* __restrict__ dw_acc) {
    int row = blockIdx.x * 8 + (threadIdx.x >> 5);
    int c   = threadIdx.x & 31;
    int code = codes_i[row];
    if (c == 0) atomicAdd(&cnt_acc[code], 1.0f);
    const float* zr = z + (size_t)row * D_DIM;
    float* dr = dw_acc + (size_t)code * D_DIM;
    #pragma unroll
    for (int d = c; d < D_DIM; d += 32) atomicAdd(&dr[d], zr[d]);
}

// ---------------- K6: new_cs (in-place) + nsum ----------------------------
__global__ __launch_bounds__(256)
void cs_kernel(const float* __restrict__ ema_cs, float* __restrict__ cs_out,
               float* __restrict__ nsum) {
    __shared__ float wsum[4];
    int i = blockIdx.x * 256 + threadIdx.x;
    float v = ema_cs[i] * DECAY + (1.0f - DECAY) * cs_out[i];
    cs_out[i] = v;
    float s = v;
    #pragma unroll
    for (int off = 32; off; off >>= 1) s += __shfl_down(s, off);
    int lane = threadIdx.x & 63, wid = threadIdx.x >> 6;
    if (lane == 0) wsum[wid] = s;
    __syncthreads();
    if (threadIdx.x == 0)
        atomicAdd(nsum, wsum[0] + wsum[1] + wsum[2] + wsum[3]);
}

// ---------------- K7: new_ema_w (in-place) + new_weight -------------------
__global__ __launch_bounds__(256)
void weight_kernel(const float* __restrict__ ema_w, const float* __restrict__ cs,
                   const float* __restrict__ nsum_p,
                   float* __restrict__ emaw_out, float* __restrict__ w_out) {
    int i = blockIdx.x * 256 + threadIdx.x;
    float dw = emaw_out[i];
    float ne = ema_w[i] * DECAY + (1.0f - DECAY) * dw;
    emaw_out[i] = ne;
    int k = i >> 9;
    float n = *nsum_p;
    float csize = (cs[k] + EPS_VQ) / (n + (float)K_CODES * EPS_VQ) * n;
    w_out[i] = ne / csize;
}

// ---------------- K8: z_q gather + loss -----------------------------------
__global__ __launch_bounds__(256)
void gather_loss_kernel(const float* __restrict__ z, const int* __restrict__ codes,
                        const float* __restrict__ w, float* __restrict__ zq,
                        float* __restrict__ loss_acc) {
    __shared__ float wsum[4];
    int row  = blockIdx.x * 4 + (threadIdx.x >> 6);
    int lane = threadIdx.x & 63;
    int code = codes[row];
    const float* zr = z + (size_t)row * D_DIM;
    const float* wr = w + (size_t)code * D_DIM;
    float s = 0.0f;
    #pragma unroll
    for (int d = lane; d < D_DIM; d += 64) {
        float qv = wr[d];
        float diff = qv - zr[d];
        s += diff * diff;
        zq[(size_t)row * D_DIM + d] = qv;
    }
    #pragma unroll
    for (int off = 32; off; off >>= 1) s += __shfl_down(s, off);
    int wid = threadIdx.x >> 6;
    if (lane == 0) wsum[wid] = s;
    __syncthreads();
    if (threadIdx.x == 0)
        atomicAdd(loss_acc, wsum[0] + wsum[1] + wsum[2] + wsum[3]);
}

__global__ void finalize_kernel(const float* __restrict__ loss_acc,
                                float* __restrict__ out0) {
    *out0 = COMMIT * (*loss_acc) / 16777216.0f;
}

// ---------------- launch --------------------------------------------------
extern "C" void kernel_launch(void* const* d_in, const int* in_sizes, int n_in,
                              void* d_out, int out_size, void* d_ws, size_t ws_size,
                              hipStream_t stream) {
    const float* z      = (const float*)d_in[0];
    const float* weight = (const float*)d_in[1];
    const float* ema_cs = (const float*)d_in[2];
    const float* ema_w  = (const float*)d_in[3];

    float* out       = (float*)d_out;
    float* out_loss  = out;
    float* out_zq    = out + 1;
    float* out_codes = out + 16777217;
    float* out_w     = out + 16809985;
    float* out_cs    = out + 21004289;
    float* out_emaw  = out + 21012481;

    // f16 operands in z_q region (z_q written last); partials in tail region
    half_t* A_hi = (half_t*)(out + 4);
    half_t* B_hi = (half_t*)(out + 8388612);
    uint4*  partial = (uint4*)(out + 16809988);   // 16B-aligned, 16MB used

    char* ws = (char*)d_ws;
    float* wsq      = (float*)ws;                 // 32KB
    int*   codes_i  = (int*)(ws + 32768);         // 128KB
    int*   cnt      = (int*)(ws + 163840);
    float* nsum     = (float*)(ws + 163844);
    float* loss_acc = (float*)(ws + 163848);
    int*   list     = (int*)(ws + 163856);        // 128KB
    u64*   exact    = (u64*)(ws + 294928);        // 256KB

    hipMemsetAsync(cnt, 0, 16, stream);                     // cnt+nsum+loss
    hipMemsetAsync(exact, 0xFF, N_VEC * 8, stream);

    conv_half_kernel<<<N_VEC * D_DIM / 1024, 256, 0, stream>>>(z, A_hi);
    prep_w_kernel<<<K_CODES / 4, 256, 0, stream>>>(weight, B_hi, wsq);

    dist1_kernel<<<4096, 512, 0, stream>>>(A_hi, B_hi, wsq, partial);

    reduce_top2_kernel<<<N_VEC / 256, 256, 0, stream>>>(partial, codes_i,
                                                        out_codes, cnt, list);

    // partials dead -> accumulators may now be zeroed
    hipMemsetAsync(out_cs, 0, 8192 * 4, stream);
    hipMemsetAsync(out_emaw, 0, (size_t)4194304 * 4, stream);

    dim3 gr(K_CODES / 64, 64);                              // 128 x 64
    refine2_kernel<<<gr, 256, 0, stream>>>(z, weight, wsq, cnt, list, exact);
    refine_fix_kernel<<<64, 256, 0, stream>>>(cnt, list, exact,
                                              codes_i, out_codes);

    scatter_kernel<<<N_VEC / 8, 256, 0, stream>>>(codes_i, z, out_cs, out_emaw);
    cs_kernel<<<K_CODES / 256, 256, 0, stream>>>(ema_cs, out_cs, nsum);
    weight_kernel<<<4194304 / 256, 256, 0, stream>>>(ema_w, out_cs, nsum,
                                                     out_emaw, out_w);
    gather_loss_kernel<<<N_VEC / 4, 256, 0, stream>>>(z, codes_i, out_w,
                                                      out_zq, loss_acc);
    finalize_kernel<<<1, 1, 0, stream>>>(loss_acc, out_loss);
}